// Round 1
// baseline (1581.672 us; speedup 1.0000x reference)
//
#include <hip/hip_runtime.h>

#define HDIM 64
#define RDIM 300

typedef float f32x4 __attribute__((ext_vector_type(4)));
typedef short bf16x8 __attribute__((ext_vector_type(8)));

__device__ __forceinline__ unsigned short f2bf(float f) {
  union { float f; unsigned u; } v; v.f = f;
  unsigned r = v.u + 0x7fffu + ((v.u >> 16) & 1u);   // round-to-nearest-even
  return (unsigned short)(r >> 16);
}
__device__ __forceinline__ float bf2f(unsigned short s) {
  union { unsigned u; float f; } v; v.u = ((unsigned)s) << 16;
  return v.f;
}
// shifted softplus: softplus(x) - log(2), numerically stable
__device__ __forceinline__ float sspf(float x) {
  float a = fabsf(x);
  return fmaxf(x, 0.0f) + log1pf(__expf(-a)) - 0.69314718055994531f;
}
__device__ __forceinline__ bf16x8 cvt8(f32x4 c0, f32x4 c1) {
  bf16x8 a;
  a[0] = (short)f2bf(c0[0]); a[1] = (short)f2bf(c0[1]);
  a[2] = (short)f2bf(c0[2]); a[3] = (short)f2bf(c0[3]);
  a[4] = (short)f2bf(c1[0]); a[5] = (short)f2bf(c1[1]);
  a[6] = (short)f2bf(c1[2]); a[7] = (short)f2bf(c1[3]);
  return a;
}

// ---------------- Kernel A: h = x @ w1 + b1 -> bf16 [N,64] ----------------
__global__ __launch_bounds__(256) void node_h_kernel(
    const float* __restrict__ x, const float* __restrict__ w1,
    const float* __restrict__ b1, unsigned short* __restrict__ h_bf, int N)
{
  __shared__ __attribute__((aligned(16))) unsigned short wT[64][72];
  const int tid = threadIdx.x;
  for (int idx = tid; idx < 64 * 32; idx += 256) {
    int n = idx & 63, kp = idx >> 6, k = kp * 2;
    unsigned lo = f2bf(w1[k * 64 + n]);
    unsigned hi = f2bf(w1[(k + 1) * 64 + n]);
    *(unsigned*)&wT[n][k] = lo | (hi << 16);
  }
  __syncthreads();
  const int wv = tid >> 6, lane = tid & 63, lg = lane >> 4, lr = lane & 15;
  const int kbase = lg * 8;
  float bv[4];
  #pragma unroll
  for (int t = 0; t < 4; ++t) bv[t] = b1[t * 16 + lr];
  const f32x4 z4 = {0.f, 0.f, 0.f, 0.f};
  const int nwt = N >> 4;  // 16 nodes per wave-tile
  for (int wt = (int)blockIdx.x * 4 + wv; wt < nwt; wt += (int)gridDim.x * 4) {
    const int n0 = wt << 4;
    const float* xrow = x + (long)(n0 + lr) * HDIM;
    f32x4 acc[4] = {z4, z4, z4, z4};
    #pragma unroll
    for (int kk = 0; kk < 2; ++kk) {
      const int ko = kk * 32 + kbase;
      f32x4 c0 = *(const f32x4*)(xrow + ko);
      f32x4 c1 = *(const f32x4*)(xrow + ko + 4);
      bf16x8 a = cvt8(c0, c1);
      #pragma unroll
      for (int t = 0; t < 4; ++t) {
        bf16x8 b = *(const bf16x8*)&wT[t * 16 + lr][ko];
        acc[t] = __builtin_amdgcn_mfma_f32_16x16x32_bf16(a, b, acc[t], 0, 0, 0);
      }
    }
    #pragma unroll
    for (int r = 0; r < 4; ++r) {
      const long n = n0 + lg * 4 + r;  // C-layout row = (lane>>4)*4 + reg
      #pragma unroll
      for (int t = 0; t < 4; ++t)
        h_bf[n * HDIM + t * 16 + lr] = f2bf(acc[t][r] + bv[t]);
    }
  }
}

// ------- Kernel B: filt = ssp(ssp(rbf@fw1+fb1)@fw2+fb2); atomic scatter -------
__global__ __launch_bounds__(256, 2) void edge_kernel(
    const float* __restrict__ rbf, const int* __restrict__ ei,
    const unsigned short* __restrict__ h_bf,
    const float* __restrict__ fw1, const float* __restrict__ fb1,
    const float* __restrict__ fw2, const float* __restrict__ fb2,
    float* __restrict__ accum, int E, int N)
{
  // fw1T[n][k]: row stride 328 ushorts = 656B = 41*16 -> 16B aligned, banks 4n%32 -> 2-way max
  __shared__ __attribute__((aligned(16))) unsigned short fw1T[64][328];
  __shared__ __attribute__((aligned(16))) unsigned short fw2T[64][72];
  __shared__ __attribute__((aligned(16))) unsigned short filtb[4][16][72]; // per-wave, no barrier needed
  const int tid = threadIdx.x;
  for (int idx = tid; idx < 64 * 150; idx += 256) {     // k = 0..299 (pairs)
    int n = idx & 63, kp = idx >> 6, k = kp * 2;
    unsigned lo = f2bf(fw1[(long)k * 64 + n]);
    unsigned hi = f2bf(fw1[(long)(k + 1) * 64 + n]);
    *(unsigned*)&fw1T[n][k] = lo | (hi << 16);
  }
  for (int idx = tid; idx < 64 * 10; idx += 256) {      // zero-pad k = 300..319
    int n = idx & 63, kp = idx >> 6;
    *(unsigned*)&fw1T[n][300 + kp * 2] = 0u;
  }
  for (int idx = tid; idx < 64 * 32; idx += 256) {
    int n = idx & 63, kp = idx >> 6, k = kp * 2;
    unsigned lo = f2bf(fw2[k * 64 + n]);
    unsigned hi = f2bf(fw2[(k + 1) * 64 + n]);
    *(unsigned*)&fw2T[n][k] = lo | (hi << 16);
  }
  __syncthreads();

  const int wv = tid >> 6, lane = tid & 63, lg = lane >> 4, lr = lane & 15;
  const int kbase = lg * 8;
  float fb1v[4], fb2v[4];
  #pragma unroll
  for (int t = 0; t < 4; ++t) { fb1v[t] = fb1[t * 16 + lr]; fb2v[t] = fb2[t * 16 + lr]; }
  const f32x4 z4 = {0.f, 0.f, 0.f, 0.f};
  const int ntiles = E >> 6;  // 64 edges per block-tile, 16 per wave
  for (int tile = blockIdx.x; tile < ntiles; tile += gridDim.x) {
    const int e0 = (tile << 6) + (wv << 4);
    const float* rrow = rbf + (long)(e0 + lr) * RDIM;   // A-row: edge = e0 + (lane&15)
    f32x4 acc[4] = {z4, z4, z4, z4};
    // GEMM1: K=300 padded to 320, 10 k-steps of 32, prefetched
    f32x4 p0 = __builtin_nontemporal_load((const f32x4*)(rrow + kbase));
    f32x4 p1 = __builtin_nontemporal_load((const f32x4*)(rrow + kbase + 4));
    #pragma unroll
    for (int kk = 0; kk < 10; ++kk) {
      f32x4 c0 = p0, c1 = p1;
      if (kk < 8) {
        const float* q = rrow + (kk + 1) * 32 + kbase;
        p0 = __builtin_nontemporal_load((const f32x4*)q);
        p1 = __builtin_nontemporal_load((const f32x4*)(q + 4));
      } else if (kk == 8) {  // guarded prefetch for the 288..319 tail (valid < 300)
        const int kb = 288 + kbase;
        #pragma unroll
        for (int j = 0; j < 4; ++j) p0[j] = (kb + j < RDIM) ? rrow[kb + j] : 0.0f;
        #pragma unroll
        for (int j = 0; j < 4; ++j) p1[j] = (kb + 4 + j < RDIM) ? rrow[kb + 4 + j] : 0.0f;
      }
      bf16x8 a = cvt8(c0, c1);
      const int ko = kk * 32 + kbase;
      #pragma unroll
      for (int t = 0; t < 4; ++t) {
        bf16x8 b = *(const bf16x8*)&fw1T[t * 16 + lr][ko];
        acc[t] = __builtin_amdgcn_mfma_f32_16x16x32_bf16(a, b, acc[t], 0, 0, 0);
      }
    }
    // epilogue 1: bias + ssp -> per-wave LDS (re-layout C->A for GEMM2)
    #pragma unroll
    for (int r = 0; r < 4; ++r) {
      const int row = lg * 4 + r;
      #pragma unroll
      for (int t = 0; t < 4; ++t)
        filtb[wv][row][t * 16 + lr] = f2bf(sspf(acc[t][r] + fb1v[t]));
    }
    // GEMM2: [16,64] @ fw2
    f32x4 acc2[4] = {z4, z4, z4, z4};
    #pragma unroll
    for (int kk = 0; kk < 2; ++kk) {
      const int ko = kk * 32 + kbase;
      bf16x8 a2 = *(const bf16x8*)&filtb[wv][lr][ko];
      #pragma unroll
      for (int t = 0; t < 4; ++t) {
        bf16x8 b = *(const bf16x8*)&fw2T[t * 16 + lr][ko];
        acc2[t] = __builtin_amdgcn_mfma_f32_16x16x32_bf16(a2, b, acc2[t], 0, 0, 0);
      }
    }
    // epilogue 2: bias + ssp, gather h[src], scatter-add to accum[dst]
    #pragma unroll
    for (int r = 0; r < 4; ++r) {
      const int eg = e0 + lg * 4 + r;
      int s = ei[eg], d = ei[E + eg];
      s = s < 0 ? 0 : (s >= N ? N - 1 : s);   // defensive clamp (dtype contract)
      d = d < 0 ? 0 : (d >= N ? N - 1 : d);
      const unsigned short* hrow = h_bf + (long)s * HDIM;
      float* arow = accum + (long)d * HDIM;
      #pragma unroll
      for (int t = 0; t < 4; ++t) {
        float fv = sspf(acc2[t][r] + fb2v[t]);
        float hv = bf2f(hrow[t * 16 + lr]);
        unsafeAtomicAdd(&arow[t * 16 + lr], hv * fv);
      }
    }
  }
}

// ------- Kernel C: out = ssp(acc@w2+b2)@w3 + b3 + x -------
__global__ __launch_bounds__(256) void node_out_kernel(
    const float* __restrict__ accum,
    const float* __restrict__ w2, const float* __restrict__ b2,
    const float* __restrict__ w3, const float* __restrict__ b3,
    const float* __restrict__ x, float* __restrict__ out, int N)
{
  __shared__ __attribute__((aligned(16))) unsigned short w2T[64][72];
  __shared__ __attribute__((aligned(16))) unsigned short w3T[64][72];
  __shared__ __attribute__((aligned(16))) unsigned short filtb[4][16][72];
  const int tid = threadIdx.x;
  for (int idx = tid; idx < 64 * 32; idx += 256) {
    int n = idx & 63, kp = idx >> 6, k = kp * 2;
    *(unsigned*)&w2T[n][k] =
        (unsigned)f2bf(w2[k * 64 + n]) | ((unsigned)f2bf(w2[(k + 1) * 64 + n]) << 16);
    *(unsigned*)&w3T[n][k] =
        (unsigned)f2bf(w3[k * 64 + n]) | ((unsigned)f2bf(w3[(k + 1) * 64 + n]) << 16);
  }
  __syncthreads();
  const int wv = tid >> 6, lane = tid & 63, lg = lane >> 4, lr = lane & 15;
  const int kbase = lg * 8;
  float b2v[4], b3v[4];
  #pragma unroll
  for (int t = 0; t < 4; ++t) { b2v[t] = b2[t * 16 + lr]; b3v[t] = b3[t * 16 + lr]; }
  const f32x4 z4 = {0.f, 0.f, 0.f, 0.f};
  const int nwt = N >> 4;
  for (int wt = (int)blockIdx.x * 4 + wv; wt < nwt; wt += (int)gridDim.x * 4) {
    const int n0 = wt << 4;
    const float* arow = accum + (long)(n0 + lr) * HDIM;
    f32x4 acc[4] = {z4, z4, z4, z4};
    #pragma unroll
    for (int kk = 0; kk < 2; ++kk) {
      const int ko = kk * 32 + kbase;
      f32x4 c0 = *(const f32x4*)(arow + ko);
      f32x4 c1 = *(const f32x4*)(arow + ko + 4);
      bf16x8 a = cvt8(c0, c1);
      #pragma unroll
      for (int t = 0; t < 4; ++t) {
        bf16x8 b = *(const bf16x8*)&w2T[t * 16 + lr][ko];
        acc[t] = __builtin_amdgcn_mfma_f32_16x16x32_bf16(a, b, acc[t], 0, 0, 0);
      }
    }
    #pragma unroll
    for (int r = 0; r < 4; ++r) {
      const int row = lg * 4 + r;
      #pragma unroll
      for (int t = 0; t < 4; ++t)
        filtb[wv][row][t * 16 + lr] = f2bf(sspf(acc[t][r] + b2v[t]));
    }
    f32x4 acc2[4] = {z4, z4, z4, z4};
    #pragma unroll
    for (int kk = 0; kk < 2; ++kk) {
      const int ko = kk * 32 + kbase;
      bf16x8 a2 = *(const bf16x8*)&filtb[wv][lr][ko];
      #pragma unroll
      for (int t = 0; t < 4; ++t) {
        bf16x8 b = *(const bf16x8*)&w3T[t * 16 + lr][ko];
        acc2[t] = __builtin_amdgcn_mfma_f32_16x16x32_bf16(a2, b, acc2[t], 0, 0, 0);
      }
    }
    #pragma unroll
    for (int r = 0; r < 4; ++r) {
      const long n = n0 + lg * 4 + r;
      #pragma unroll
      for (int t = 0; t < 4; ++t) {
        const long o = n * HDIM + t * 16 + lr;
        out[o] = acc2[t][r] + b3v[t] + x[o];
      }
    }
  }
}

extern "C" void kernel_launch(void* const* d_in, const int* in_sizes, int n_in,
                              void* d_out, int out_size, void* d_ws, size_t ws_size,
                              hipStream_t stream)
{
  const float* x   = (const float*)d_in[0];
  const int*   ei  = (const int*)d_in[1];
  const float* rbf = (const float*)d_in[2];
  const float* w1  = (const float*)d_in[3];
  const float* b1  = (const float*)d_in[4];
  const float* fw1 = (const float*)d_in[5];
  const float* fb1 = (const float*)d_in[6];
  const float* fw2 = (const float*)d_in[7];
  const float* fb2 = (const float*)d_in[8];
  const float* w2  = (const float*)d_in[9];
  const float* b2  = (const float*)d_in[10];
  const float* w3  = (const float*)d_in[11];
  const float* b3  = (const float*)d_in[12];
  float* out = (float*)d_out;
  const int N = in_sizes[0] / HDIM;
  const int E = in_sizes[1] / 2;

  unsigned short* h_bf = (unsigned short*)d_ws;                       // [N,64] bf16
  size_t off = ((size_t)N * HDIM * sizeof(unsigned short) + 255) & ~(size_t)255;
  float* accum = (float*)((char*)d_ws + off);                         // [N,64] f32

  hipMemsetAsync(accum, 0, (size_t)N * HDIM * sizeof(float), stream);
  node_h_kernel<<<1024, 256, 0, stream>>>(x, w1, b1, h_bf, N);
  edge_kernel<<<1024, 256, 0, stream>>>(rbf, ei, h_bf, fw1, fb1, fw2, fb2, accum, E, N);
  node_out_kernel<<<1024, 256, 0, stream>>>(accum, w2, b2, w3, b3, x, out, N);
}